// Round 14
// baseline (214.050 us; speedup 1.0000x reference)
//
#include <hip/hip_runtime.h>

// GraphEmbeddings interaction network — swapped-operand MFMA, sigma in-register
// fr1->fr2 handoff. R14 = R13 + fo/reduce fused into edge via per-batch atomic
// ticket (last of 32 blocks per batch runs fo+reduce, reusing Sl LDS). 2 launches.

#define NB 64
#define NF 16
#define NP 128

typedef _Float16 f16x8 __attribute__((ext_vector_type(8)));
typedef _Float16 f16x2 __attribute__((ext_vector_type(2)));
typedef float    f32x4 __attribute__((ext_vector_type(4)));

__device__ __forceinline__ f16x2 cvt_pk(float a, float b) {
    return __builtin_bit_cast(f16x2, __builtin_amdgcn_cvt_pkrtz(a, b));
}
__device__ __forceinline__ unsigned bc32(f16x2 h) {
    return __builtin_bit_cast(unsigned, h);
}

// ---------------- prep ----------------
// blocks 0..1535   : Rc ([node][96]) and Sc2 (k-planes), fp16
// block 1536       : consts c1/c2/c3/c4 (f32) + zero the 64 batch counters
// blocks 1537..1568: w1f + w2f(sigma) ; 1569..1592: w3f + w4f(sigma)
// blocks 1593..1624: xt16[node][16]
__global__ void prep_kernel(const float* __restrict__ x, const float* __restrict__ w0,
                            const float* __restrict__ w1, const float* __restrict__ w2,
                            const float* __restrict__ w3, const float* __restrict__ w4,
                            _Float16* __restrict__ w1f, _Float16* __restrict__ w3f,
                            float* __restrict__ cs, _Float16* __restrict__ xt16,
                            _Float16* __restrict__ Rch, _Float16* __restrict__ Sc2,
                            int* __restrict__ counters,
    const float* b0, const float* g0, const float* be0, const float* m0, const float* v0,
    const float* b1, const float* g1, const float* be1, const float* m1, const float* v1,
    const float* b2, const float* g2, const float* be2, const float* m2, const float* v2,
    const float* b3, const float* g3, const float* be3, const float* m3, const float* v3,
    const float* b4, const float* g4, const float* be4, const float* m4, const float* v4)
{
    const int bi = blockIdx.x;
    const int t = threadIdx.x;
    if (bi < 1536) {
        int idx = bi * 256 + t;            // B*P*48 (2 ch per thread)
        int c2i = idx % 48;
        int node = idx / 48;
        int p = node & (NP - 1);
        int b = node >> 7;
        int ch0 = c2i * 2, ch1 = ch0 + 1;
        float sa = g0[ch0] * rsqrtf(v0[ch0] + 1e-3f);
        float sb = g0[ch1] * rsqrtf(v0[ch1] + 1e-3f);
        float ca = (b0[ch0] - m0[ch0]) * sa + be0[ch0];
        float cb = (b0[ch1] - m0[ch1]) * sb + be0[ch1];
        const float* xb = x + b * NF * NP + p;
        float r0 = 0.f, r1 = 0.f, s0 = 0.f, s1 = 0.f;
#pragma unroll
        for (int f = 0; f < NF; ++f) {
            float xv = xb[f * NP];
            float2 wr = *(const float2*)&w0[f * 96 + ch0];
            float2 ws = *(const float2*)&w0[(NF + f) * 96 + ch0];
            r0 += xv * wr.x; r1 += xv * wr.y;
            s0 += xv * ws.x; s1 += xv * ws.y;
        }
        f16x2 rv; rv[0] = (_Float16)(r0 * sa + ca); rv[1] = (_Float16)(r1 * sb + cb);
        f16x2 sv; sv[0] = (_Float16)(s0 * sa);      sv[1] = (_Float16)(s1 * sb);
        *(f16x2*)&Rch[node * 96 + ch0] = rv;
        int ks = ch0 >> 5;                 // plane (pair stays within one plane)
        *(f16x2*)&Sc2[((b * 3 + ks) * NP + p) * 32 + (ch0 - ks * 32)] = sv;
    } else if (bi == 1536) {
        if (t < 64) {                      // c1 f32
            float s = g1[t] * rsqrtf(v1[t] + 1e-3f);
            cs[192 + t] = (b1[t] - m1[t]) * s + be1[t];
        }
        if (t < 32) {                      // c2 f32
            float s = g2[t] * rsqrtf(v2[t] + 1e-3f);
            cs[352 + t] = (b2[t] - m2[t]) * s + be2[t];
        }
        if (t < 64) {                      // c3 f32
            float s = g3[t] * rsqrtf(v3[t] + 1e-3f);
            cs[384 + t] = (b3[t] - m3[t]) * s + be3[t];
        }
        if (t < 32) {                      // c4 f32
            float s = g4[t] * rsqrtf(v4[t] + 1e-3f);
            cs[512 + t] = (b4[t] - m4[t]) * s + be4[t];
        }
        if (t >= 128 && t < 192) counters[t - 128] = 0;   // zero batch tickets
    } else if (bi < 1569) {
        int i = (bi - 1537) * 256 + t;        // 0..8191
        if (i < 6144) {                       // w1f[kb][n][j] = W1[kb*8+j][n]*s1[n]
            int j = i & 7, n = (i >> 3) & 63, kb = i >> 9;
            float s1 = g1[n] * rsqrtf(v1[n] + 1e-3f);
            w1f[i] = (_Float16)(w1[(kb * 8 + j) * 64 + n] * s1);
        } else {                              // w2f: sigma-permuted K, s2-scaled
            int i2 = i - 6144;
            int j = i2 & 7, n = (i2 >> 3) & 31, kb = i2 >> 8;
            int ks = kb >> 2, g = kb & 3;
            int src = (2 * ks + (j >> 2)) * 16 + 4 * g + (j & 3);
            float s2 = g2[n] * rsqrtf(v2[n] + 1e-3f);
            w1f[6144 + i2] = (_Float16)(w2[src * 32 + n] * s2);
        }
    } else if (bi < 1593) {
        int i = (bi - 1569) * 256 + t;        // 0..6143
        if (i < 4096) {                       // w3f[kb][n][j] = fo0[kb*8+j][n]*s3[n], pad k>=48
            int j = i & 7, n = (i >> 3) & 63, kb = i >> 9;
            int k = kb * 8 + j;
            float s3 = g3[n] * rsqrtf(v3[n] + 1e-3f);
            w3f[i] = (k < 48) ? (_Float16)(w3[k * 64 + n] * s3) : (_Float16)0.f;
        } else {                              // w4f: sigma-permuted, s4-scaled
            int i2 = i - 4096;
            int j = i2 & 7, n = (i2 >> 3) & 31, kb = i2 >> 8;
            int ks = kb >> 2, g = kb & 3;
            int src = (2 * ks + (j >> 2)) * 16 + 4 * g + (j & 3);
            float s4 = g4[n] * rsqrtf(v4[n] + 1e-3f);
            w3f[4096 + i2] = (_Float16)(w4[src * 32 + n] * s4);
        }
    } else {
        int n = (bi - 1593) * 256 + t;        // 0..8191 nodes
        int b = n >> 7, pn = n & 127;
        _Float16 tmp[16];
#pragma unroll
        for (int f = 0; f < NF; ++f) tmp[f] = (_Float16)x[(b * NF + f) * NP + pn];
        *(f16x8*)&xt16[n * 16]     = *(f16x8*)&tmp[0];
        *(f16x8*)&xt16[n * 16 + 8] = *(f16x8*)&tmp[8];
    }
}

// ---------------- edge MLP + ticketed fo/reduce tail ----------------
// Grid: 2048 blocks x 256 thr. Block = (b, 4 receivers); 32 blocks per batch.
// Last block of each batch (atomic ticket) runs fo MLP + reduce for that batch.
__global__ __launch_bounds__(256) void edge_kernel(
    const _Float16* __restrict__ Rch, const _Float16* __restrict__ Sc2,
    const _Float16* __restrict__ w1f,      // w1f(6144) || w2f(2048)
    const _Float16* __restrict__ w3f,      // w3f(4096) || w4f(2048)
    const float* __restrict__ cs, const _Float16* __restrict__ xt16,
    int* __restrict__ counters,
    float* __restrict__ aggh,              // [node][32] f32
    float* __restrict__ out)               // [B][32] f32
{
    __shared__ _Float16 Sl[3 * 128 * 40];  // 30720 B padded slab (reused by tail)
    __shared__ _Float16 bw2L[2048];        // 4 KB fr2 weight frags
    __shared__ int lastFlag;

    const int tid  = threadIdx.x;
    const int w    = tid >> 6;
    const int lane = tid & 63;
    const int g    = lane >> 4;
    const int l15  = lane & 15;
    const int blk  = blockIdx.x;
    const int b    = blk >> 5;
    const int p    = (blk & 31) * 4 + w;

    // stage fr2 weights + Sc2 slab (contiguous 12288 f16 = 1536 uint4)
    ((uint4*)bw2L)[tid] = ((const uint4*)(w1f + 6144))[tid];
    {
        const uint4* src = (const uint4*)(Sc2 + (size_t)b * 3 * NP * 32);
#pragma unroll
        for (int i = 0; i < 6; ++i) {
            int idx = tid + i * 256;       // 0..1535
            int row = idx >> 2, c8 = idx & 3;
            *(uint4*)&Sl[row * 40 + c8 * 8] = src[idx];
        }
    }
    __syncthreads();

    // ---- fr1 weights + per-lane consts in registers ----
    f16x8 bw1[3][4];
#pragma unroll
    for (int ks = 0; ks < 3; ++ks)
#pragma unroll
        for (int mt = 0; mt < 4; ++mt)
            bw1[ks][mt] = *(const f16x8*)&w1f[(((ks * 4 + g) * 64) + mt * 16 + l15) * 8];
    f16x8 rc[3];
#pragma unroll
    for (int ks = 0; ks < 3; ++ks)
        rc[ks] = *(const f16x8*)&Rch[(size_t)(b * NP + p) * 96 + ks * 32 + g * 8];
    f16x2 c1pk[4][2];
#pragma unroll
    for (int mt = 0; mt < 4; ++mt) {
        f32x4 cf = *(const f32x4*)&cs[192 + mt * 16 + 4 * g];
        c1pk[mt][0] = cvt_pk(cf[0], cf[1]);
        c1pk[mt][1] = cvt_pk(cf[2], cf[3]);
    }
    f32x4 c2v[2];
#pragma unroll
    for (int mt = 0; mt < 2; ++mt)
        c2v[mt] = *(const f32x4*)&cs[352 + mt * 16 + 4 * g];

    f32x4 sums[2];
    sums[0] = (f32x4){0.f, 0.f, 0.f, 0.f};
    sums[1] = (f32x4){0.f, 0.f, 0.f, 0.f};

#pragma unroll
    for (int it = 0; it < 8; ++it) {
        const int row = it * 16 + l15;     // edge (sender) index
        f16x8 bf[3];
#pragma unroll
        for (int ks = 0; ks < 3; ++ks) {
            f16x8 sv = *(const f16x8*)&Sl[(ks * NP + row) * 40 + g * 8];
            f16x8 tv = sv + rc[ks];
            f16x8 zz = {};
            bf[ks] = __builtin_elementwise_max(tv, zz);
        }
        f32x4 acc[4];
#pragma unroll
        for (int mt = 0; mt < 4; ++mt) acc[mt] = (f32x4){0.f, 0.f, 0.f, 0.f};
#pragma unroll
        for (int ks = 0; ks < 3; ++ks)
#pragma unroll
            for (int mt = 0; mt < 4; ++mt)
                acc[mt] = __builtin_amdgcn_mfma_f32_16x16x32_f16(bw1[ks][mt], bf[ks], acc[mt], 0, 0, 0);
        f16x2 pw[4][2];
#pragma unroll
        for (int mt = 0; mt < 4; ++mt)
#pragma unroll
            for (int rp = 0; rp < 2; ++rp) {
                f16x2 hh = cvt_pk(acc[mt][2 * rp], acc[mt][2 * rp + 1]);
                hh = hh + c1pk[mt][rp];
                f16x2 zz = {};
                pw[mt][rp] = __builtin_elementwise_max(hh, zz);
            }
        f32x4 acc2[2];
        acc2[0] = c2v[0];
        acc2[1] = c2v[1];
#pragma unroll
        for (int ks = 0; ks < 2; ++ks) {
            uint4 uu;
            uu.x = bc32(pw[2 * ks][0]);
            uu.y = bc32(pw[2 * ks][1]);
            uu.z = bc32(pw[2 * ks + 1][0]);
            uu.w = bc32(pw[2 * ks + 1][1]);
            f16x8 u = __builtin_bit_cast(f16x8, uu);
#pragma unroll
            for (int mt = 0; mt < 2; ++mt) {
                f16x8 a2 = *(const f16x8*)&bw2L[(((ks * 4 + g) * 32) + mt * 16 + l15) * 8];
                acc2[mt] = __builtin_amdgcn_mfma_f32_16x16x32_f16(a2, u, acc2[mt], 0, 0, 0);
            }
        }
#pragma unroll
        for (int mt = 0; mt < 2; ++mt)
#pragma unroll
            for (int r = 0; r < 4; ++r) {
                float v = fmaxf(acc2[mt][r], 0.f);
                sums[mt][r] += (row != p) ? v : 0.f;
            }
    }

    // ---- reduce over the 16 edge-lanes within each group; store partials ----
#pragma unroll
    for (int mt = 0; mt < 2; ++mt)
#pragma unroll
        for (int d = 1; d <= 8; d <<= 1) {
            sums[mt][0] += __shfl_xor(sums[mt][0], d, 64);
            sums[mt][1] += __shfl_xor(sums[mt][1], d, 64);
            sums[mt][2] += __shfl_xor(sums[mt][2], d, 64);
            sums[mt][3] += __shfl_xor(sums[mt][3], d, 64);
        }
    if (l15 == 0) {
#pragma unroll
        for (int mt = 0; mt < 2; ++mt)
            *(f32x4*)&aggh[(size_t)(b * NP + p) * 32 + mt * 16 + 4 * g] = sums[mt];
    }

    // ---- per-batch ticket: last of 32 blocks runs fo + reduce ----
    __threadfence();                   // make this block's aggh stores visible
    __syncthreads();                   // all 4 waves' stores issued+fenced
    if (tid == 0) lastFlag = (atomicAdd(&counters[b], 1) == 31);
    __syncthreads();
    if (!lastFlag) return;
    __threadfence();                   // acquire: see all 32 blocks' aggh

    // reuse Sl for reduction arrays (17.9 KB < 30.7 KB)
    float (*red)[33] = (float(*)[33])Sl;
    float* red2 = (float*)Sl + 128 * 33;

#pragma unroll
    for (int q = 0; q < 2; ++q) {
        const int nl = w * 32 + q * 16 + l15;      // node-in-batch 0..127
        const size_t node = (size_t)b * NP + nl;
        f16x8 bfo[2];
        if (g < 2) {
            bfo[0] = *(const f16x8*)&xt16[node * 16 + g * 8];
            const float* a1 = &aggh[node * 32 + 16 + g * 8];
            f16x8 t1;
#pragma unroll
            for (int j = 0; j < 8; ++j) t1[j] = (_Float16)a1[j];
            bfo[1] = t1;
        } else {
            const float* a0 = &aggh[node * 32 + (g - 2) * 8];
            f16x8 t0;
#pragma unroll
            for (int j = 0; j < 8; ++j) t0[j] = (_Float16)a0[j];
            bfo[0] = t0;
            f16x8 zz = {};
            bfo[1] = zz;
        }

        f32x4 acc3[4];
#pragma unroll
        for (int mt = 0; mt < 4; ++mt)
            acc3[mt] = *(const f32x4*)&cs[384 + mt * 16 + 4 * g];
#pragma unroll
        for (int ks = 0; ks < 2; ++ks)
#pragma unroll
            for (int mt = 0; mt < 4; ++mt) {
                f16x8 a3 = *(const f16x8*)&w3f[(((ks * 4 + g) * 64) + mt * 16 + l15) * 8];
                acc3[mt] = __builtin_amdgcn_mfma_f32_16x16x32_f16(a3, bfo[ks], acc3[mt], 0, 0, 0);
            }
        f16x2 pw3[4][2];
#pragma unroll
        for (int mt = 0; mt < 4; ++mt)
#pragma unroll
            for (int rp = 0; rp < 2; ++rp) {
                f16x2 hh = cvt_pk(acc3[mt][2 * rp], acc3[mt][2 * rp + 1]);
                f16x2 zz = {};
                pw3[mt][rp] = __builtin_elementwise_max(hh, zz);
            }
        f32x4 acc4[2];
        acc4[0] = *(const f32x4*)&cs[512 + 0 * 16 + 4 * g];
        acc4[1] = *(const f32x4*)&cs[512 + 1 * 16 + 4 * g];
#pragma unroll
        for (int ks = 0; ks < 2; ++ks) {
            uint4 uu;
            uu.x = bc32(pw3[2 * ks][0]);
            uu.y = bc32(pw3[2 * ks][1]);
            uu.z = bc32(pw3[2 * ks + 1][0]);
            uu.w = bc32(pw3[2 * ks + 1][1]);
            f16x8 u = __builtin_bit_cast(f16x8, uu);
#pragma unroll
            for (int mt = 0; mt < 2; ++mt) {
                f16x8 a4 = *(const f16x8*)&w3f[4096 + (((ks * 4 + g) * 32) + mt * 16 + l15) * 8];
                acc4[mt] = __builtin_amdgcn_mfma_f32_16x16x32_f16(a4, u, acc4[mt], 0, 0, 0);
            }
        }
#pragma unroll
        for (int mt = 0; mt < 2; ++mt)
#pragma unroll
            for (int r = 0; r < 4; ++r)
                red[nl][mt * 16 + 4 * g + r] = fmaxf(acc4[mt][r], 0.f);
    }
    __syncthreads();

    // ---- reduce 128 nodes -> out[b][32] ----
    int m = tid & 31;
    int grp = tid >> 5;                // 8 groups
    float v = 0.f;
#pragma unroll
    for (int pn = 0; pn < 16; ++pn) v += red[grp * 16 + pn][m];
    red2[tid] = v;
    __syncthreads();
    if (grp < 4) red2[tid] += red2[tid + 128];
    __syncthreads();
    if (grp < 2) red2[tid] += red2[tid + 64];
    __syncthreads();
    if (grp == 0) out[b * 32 + m] = red2[tid] + red2[tid + 32];
}

extern "C" void kernel_launch(void* const* d_in, const int* in_sizes, int n_in,
                              void* d_out, int out_size, void* d_ws, size_t ws_size,
                              hipStream_t stream) {
    (void)in_sizes; (void)n_in; (void)out_size; (void)ws_size;
    const float* x    = (const float*)d_in[0];
    const float* fr0w = (const float*)d_in[1];
    const float* fr1w = (const float*)d_in[7];
    const float* fr2w = (const float*)d_in[13];
    const float* fo0w = (const float*)d_in[19];
    const float* fo1w = (const float*)d_in[25];

    float* ws = (float*)d_ws;
    float*    cs     = ws;                                   // f32[0..575]
    int*      counters = (int*)(ws + 576);                   // 64 ints (zeroed by prep)
    _Float16* Rch    = (_Float16*)(ws + 1024);               // 786432 f16
    _Float16* Sc2    = (_Float16*)(ws + 394240);             // 786432 f16
    _Float16* w1f    = (_Float16*)(ws + 787456);             // 8192 f16 (w1f||w2f)
    _Float16* w3f    = (_Float16*)(ws + 791552);             // 6144 f16 (w3f||w4f)
    _Float16* xt16   = (_Float16*)(ws + 794688);             // 131072 f16
    float*    aggh   = ws + 860224;                          // 8192*32 f32
    float*    out    = (float*)d_out;

    prep_kernel<<<1625, 256, 0, stream>>>(x, fr0w, fr1w, fr2w, fo0w, fo1w,
        w1f, w3f, cs, xt16, Rch, Sc2, counters,
        (const float*)d_in[2],  (const float*)d_in[3],  (const float*)d_in[4],
        (const float*)d_in[5],  (const float*)d_in[6],
        (const float*)d_in[8],  (const float*)d_in[9],  (const float*)d_in[10],
        (const float*)d_in[11], (const float*)d_in[12],
        (const float*)d_in[14], (const float*)d_in[15], (const float*)d_in[16],
        (const float*)d_in[17], (const float*)d_in[18],
        (const float*)d_in[20], (const float*)d_in[21], (const float*)d_in[22],
        (const float*)d_in[23], (const float*)d_in[24],
        (const float*)d_in[26], (const float*)d_in[27], (const float*)d_in[28],
        (const float*)d_in[29], (const float*)d_in[30]);

    edge_kernel<<<NB * 32, 256, 0, stream>>>(Rch, Sc2, w1f, w3f, cs, xt16,
                                             counters, aggh, out);
}

// Round 15
// 40.799 us; speedup vs baseline: 5.2464x; 5.2464x over previous
//
#include <hip/hip_runtime.h>

// GraphEmbeddings interaction network — swapped-operand MFMA, sigma in-register
// fr1->fr2 handoff. R15 = R13 (3 launches, LDS slab) + manual 1-deep prefetch
// of next-iteration Sc2 LDS reads (software pipeline). R14's atomic-ticket
// fusion REVERTED: per-block device-scope threadfence serialized 2048 blocks
// (41 -> 214 us) on 8-XCD non-coherent L2s.

#define NB 64
#define NF 16
#define NP 128

typedef _Float16 f16x8 __attribute__((ext_vector_type(8)));
typedef _Float16 f16x2 __attribute__((ext_vector_type(2)));
typedef float    f32x4 __attribute__((ext_vector_type(4)));

__device__ __forceinline__ f16x2 cvt_pk(float a, float b) {
    return __builtin_bit_cast(f16x2, __builtin_amdgcn_cvt_pkrtz(a, b));
}
__device__ __forceinline__ unsigned bc32(f16x2 h) {
    return __builtin_bit_cast(unsigned, h);
}

// ---------------- prep ----------------
// blocks 0..1535   : Rc ([node][96]) and Sc2 (k-planes [(b*3+ks)*128+a][32]), fp16
// block 1536       : consts c1 (cs+192,f32), c2 (cs+352), c3 (cs+384,f32), c4 (cs+512)
// blocks 1537..1568: w1f (W1^T s1-scaled frags) + w2f (sigma, s2-scaled)
// blocks 1569..1592: w3f (fo0^T s3-scaled, K 48->64 zero-pad) + w4f (sigma, s4)
// blocks 1593..1624: xt16[node][16] transpose of x
__global__ void prep_kernel(const float* __restrict__ x, const float* __restrict__ w0,
                            const float* __restrict__ w1, const float* __restrict__ w2,
                            const float* __restrict__ w3, const float* __restrict__ w4,
                            _Float16* __restrict__ w1f, _Float16* __restrict__ w3f,
                            float* __restrict__ cs, _Float16* __restrict__ xt16,
                            _Float16* __restrict__ Rch, _Float16* __restrict__ Sc2,
    const float* b0, const float* g0, const float* be0, const float* m0, const float* v0,
    const float* b1, const float* g1, const float* be1, const float* m1, const float* v1,
    const float* b2, const float* g2, const float* be2, const float* m2, const float* v2,
    const float* b3, const float* g3, const float* be3, const float* m3, const float* v3,
    const float* b4, const float* g4, const float* be4, const float* m4, const float* v4)
{
    const int bi = blockIdx.x;
    const int t = threadIdx.x;
    if (bi < 1536) {
        int idx = bi * 256 + t;            // B*P*48 (2 ch per thread)
        int c2i = idx % 48;
        int node = idx / 48;
        int p = node & (NP - 1);
        int b = node >> 7;
        int ch0 = c2i * 2, ch1 = ch0 + 1;
        float sa = g0[ch0] * rsqrtf(v0[ch0] + 1e-3f);
        float sb = g0[ch1] * rsqrtf(v0[ch1] + 1e-3f);
        float ca = (b0[ch0] - m0[ch0]) * sa + be0[ch0];
        float cb = (b0[ch1] - m0[ch1]) * sb + be0[ch1];
        const float* xb = x + b * NF * NP + p;
        float r0 = 0.f, r1 = 0.f, s0 = 0.f, s1 = 0.f;
#pragma unroll
        for (int f = 0; f < NF; ++f) {
            float xv = xb[f * NP];
            float2 wr = *(const float2*)&w0[f * 96 + ch0];
            float2 ws = *(const float2*)&w0[(NF + f) * 96 + ch0];
            r0 += xv * wr.x; r1 += xv * wr.y;
            s0 += xv * ws.x; s1 += xv * ws.y;
        }
        f16x2 rv; rv[0] = (_Float16)(r0 * sa + ca); rv[1] = (_Float16)(r1 * sb + cb);
        f16x2 sv; sv[0] = (_Float16)(s0 * sa);      sv[1] = (_Float16)(s1 * sb);
        *(f16x2*)&Rch[node * 96 + ch0] = rv;
        int ks = ch0 >> 5;                 // plane (pair stays within one plane)
        *(f16x2*)&Sc2[((b * 3 + ks) * NP + p) * 32 + (ch0 - ks * 32)] = sv;
    } else if (bi == 1536) {
        if (t < 64) {                      // c1 f32
            float s = g1[t] * rsqrtf(v1[t] + 1e-3f);
            cs[192 + t] = (b1[t] - m1[t]) * s + be1[t];
        }
        if (t < 32) {                      // c2 f32
            float s = g2[t] * rsqrtf(v2[t] + 1e-3f);
            cs[352 + t] = (b2[t] - m2[t]) * s + be2[t];
        }
        if (t < 64) {                      // c3 f32
            float s = g3[t] * rsqrtf(v3[t] + 1e-3f);
            cs[384 + t] = (b3[t] - m3[t]) * s + be3[t];
        }
        if (t < 32) {                      // c4 f32
            float s = g4[t] * rsqrtf(v4[t] + 1e-3f);
            cs[512 + t] = (b4[t] - m4[t]) * s + be4[t];
        }
    } else if (bi < 1569) {
        int i = (bi - 1537) * 256 + t;        // 0..8191
        if (i < 6144) {                       // w1f[kb][n][j] = W1[kb*8+j][n]*s1[n]
            int j = i & 7, n = (i >> 3) & 63, kb = i >> 9;
            float s1 = g1[n] * rsqrtf(v1[n] + 1e-3f);
            w1f[i] = (_Float16)(w1[(kb * 8 + j) * 64 + n] * s1);
        } else {                              // w2f: sigma-permuted K, s2-scaled
            int i2 = i - 6144;
            int j = i2 & 7, n = (i2 >> 3) & 31, kb = i2 >> 8;
            int ks = kb >> 2, g = kb & 3;
            int src = (2 * ks + (j >> 2)) * 16 + 4 * g + (j & 3);
            float s2 = g2[n] * rsqrtf(v2[n] + 1e-3f);
            w1f[6144 + i2] = (_Float16)(w2[src * 32 + n] * s2);
        }
    } else if (bi < 1593) {
        int i = (bi - 1569) * 256 + t;        // 0..6143
        if (i < 4096) {                       // w3f[kb][n][j] = fo0[kb*8+j][n]*s3[n], pad k>=48
            int j = i & 7, n = (i >> 3) & 63, kb = i >> 9;
            int k = kb * 8 + j;
            float s3 = g3[n] * rsqrtf(v3[n] + 1e-3f);
            w3f[i] = (k < 48) ? (_Float16)(w3[k * 64 + n] * s3) : (_Float16)0.f;
        } else {                              // w4f: sigma-permuted, s4-scaled
            int i2 = i - 4096;
            int j = i2 & 7, n = (i2 >> 3) & 31, kb = i2 >> 8;
            int ks = kb >> 2, g = kb & 3;
            int src = (2 * ks + (j >> 2)) * 16 + 4 * g + (j & 3);
            float s4 = g4[n] * rsqrtf(v4[n] + 1e-3f);
            w3f[4096 + i2] = (_Float16)(w4[src * 32 + n] * s4);
        }
    } else {
        int n = (bi - 1593) * 256 + t;        // 0..8191 nodes
        int b = n >> 7, pn = n & 127;
        _Float16 tmp[16];
#pragma unroll
        for (int f = 0; f < NF; ++f) tmp[f] = (_Float16)x[(b * NF + f) * NP + pn];
        *(f16x8*)&xt16[n * 16]     = *(f16x8*)&tmp[0];
        *(f16x8*)&xt16[n * 16 + 8] = *(f16x8*)&tmp[8];
    }
}

// ---------------- edge MLP: one wave = one receiver, 128 edges ----------------
// Grid: 2048 blocks x 256 thr = 8192 waves. Block = (b, 4 receivers).
// Sc2 slab staged in LDS (row stride 40 f16 -> conflict-free); next-iter
// ds_reads prefetched one iteration ahead (manual software pipeline).
__global__ __launch_bounds__(256) void edge_kernel(
    const _Float16* __restrict__ Rch, const _Float16* __restrict__ Sc2,
    const _Float16* __restrict__ w1f,      // w1f(6144) || w2f(2048)
    const float* __restrict__ cs,
    float* __restrict__ aggh)              // [node][32] f32
{
    __shared__ _Float16 Sl[3 * 128 * 40];  // 30720 B padded slab
    __shared__ _Float16 bw2L[2048];        // 4 KB fr2 weight frags

    const int tid  = threadIdx.x;
    const int w    = tid >> 6;
    const int lane = tid & 63;
    const int g    = lane >> 4;
    const int l15  = lane & 15;
    const int blk  = blockIdx.x;
    const int b    = blk >> 5;
    const int p    = (blk & 31) * 4 + w;

    // stage fr2 weights + Sc2 slab (contiguous 12288 f16 = 1536 uint4)
    ((uint4*)bw2L)[tid] = ((const uint4*)(w1f + 6144))[tid];
    {
        const uint4* src = (const uint4*)(Sc2 + (size_t)b * 3 * NP * 32);
#pragma unroll
        for (int i = 0; i < 6; ++i) {
            int idx = tid + i * 256;       // 0..1535
            int row = idx >> 2, c8 = idx & 3;
            *(uint4*)&Sl[row * 40 + c8 * 8] = src[idx];
        }
    }
    __syncthreads();

    // ---- fr1 weights + per-lane consts in registers ----
    f16x8 bw1[3][4];
#pragma unroll
    for (int ks = 0; ks < 3; ++ks)
#pragma unroll
        for (int mt = 0; mt < 4; ++mt)
            bw1[ks][mt] = *(const f16x8*)&w1f[(((ks * 4 + g) * 64) + mt * 16 + l15) * 8];
    f16x8 rc[3];
#pragma unroll
    for (int ks = 0; ks < 3; ++ks)
        rc[ks] = *(const f16x8*)&Rch[(size_t)(b * NP + p) * 96 + ks * 32 + g * 8];
    f16x2 c1pk[4][2];
#pragma unroll
    for (int mt = 0; mt < 4; ++mt) {
        f32x4 cf = *(const f32x4*)&cs[192 + mt * 16 + 4 * g];
        c1pk[mt][0] = cvt_pk(cf[0], cf[1]);
        c1pk[mt][1] = cvt_pk(cf[2], cf[3]);
    }
    f32x4 c2v[2];
#pragma unroll
    for (int mt = 0; mt < 2; ++mt)
        c2v[mt] = *(const f32x4*)&cs[352 + mt * 16 + 4 * g];

    f32x4 sums[2];
    sums[0] = (f32x4){0.f, 0.f, 0.f, 0.f};
    sums[1] = (f32x4){0.f, 0.f, 0.f, 0.f};

    // ---- prefetch iteration 0's slab reads ----
    f16x8 svn[3];
#pragma unroll
    for (int ks = 0; ks < 3; ++ks)
        svn[ks] = *(const f16x8*)&Sl[(ks * NP + l15) * 40 + g * 8];

#pragma unroll
    for (int it = 0; it < 8; ++it) {
        const int row = it * 16 + l15;     // edge (sender) index
        // ---- consume prefetched reads; issue next iteration's ----
        f16x8 bf[3];
#pragma unroll
        for (int ks = 0; ks < 3; ++ks) {
            f16x8 tv = svn[ks] + rc[ks];
            f16x8 zz = {};
            bf[ks] = __builtin_elementwise_max(tv, zz);
        }
        if (it < 7) {
            const int nrow = (it + 1) * 16 + l15;
#pragma unroll
            for (int ks = 0; ks < 3; ++ks)
                svn[ks] = *(const f16x8*)&Sl[(ks * NP + nrow) * 40 + g * 8];
        }
        // ---- fr1: 12 MFMAs into acc[4] ----
        f32x4 acc[4];
#pragma unroll
        for (int mt = 0; mt < 4; ++mt) acc[mt] = (f32x4){0.f, 0.f, 0.f, 0.f};
#pragma unroll
        for (int ks = 0; ks < 3; ++ks)
#pragma unroll
            for (int mt = 0; mt < 4; ++mt)
                acc[mt] = __builtin_amdgcn_mfma_f32_16x16x32_f16(bw1[ks][mt], bf[ks], acc[mt], 0, 0, 0);
        // ---- epilogue 1: pack, +c1 (f16), relu ----
        f16x2 pw[4][2];
#pragma unroll
        for (int mt = 0; mt < 4; ++mt)
#pragma unroll
            for (int rp = 0; rp < 2; ++rp) {
                f16x2 hh = cvt_pk(acc[mt][2 * rp], acc[mt][2 * rp + 1]);
                hh = hh + c1pk[mt][rp];
                f16x2 zz = {};
                pw[mt][rp] = __builtin_elementwise_max(hh, zz);
            }
        // ---- fr2 via sigma handoff (weights from LDS), acc2 init = c2 ----
        f32x4 acc2[2];
        acc2[0] = c2v[0];
        acc2[1] = c2v[1];
#pragma unroll
        for (int ks = 0; ks < 2; ++ks) {
            uint4 uu;
            uu.x = bc32(pw[2 * ks][0]);
            uu.y = bc32(pw[2 * ks][1]);
            uu.z = bc32(pw[2 * ks + 1][0]);
            uu.w = bc32(pw[2 * ks + 1][1]);
            f16x8 u = __builtin_bit_cast(f16x8, uu);
#pragma unroll
            for (int mt = 0; mt < 2; ++mt) {
                f16x8 a2 = *(const f16x8*)&bw2L[(((ks * 4 + g) * 32) + mt * 16 + l15) * 8];
                acc2[mt] = __builtin_amdgcn_mfma_f32_16x16x32_f16(a2, u, acc2[mt], 0, 0, 0);
            }
        }
        // ---- epilogue 2: relu, accumulate senders != p ----
#pragma unroll
        for (int mt = 0; mt < 2; ++mt)
#pragma unroll
            for (int r = 0; r < 4; ++r) {
                float v = fmaxf(acc2[mt][r], 0.f);
                sums[mt][r] += (row != p) ? v : 0.f;
            }
    }

    // ---- reduce over the 16 edge-lanes within each group; store partials ----
#pragma unroll
    for (int mt = 0; mt < 2; ++mt)
#pragma unroll
        for (int d = 1; d <= 8; d <<= 1) {
            sums[mt][0] += __shfl_xor(sums[mt][0], d, 64);
            sums[mt][1] += __shfl_xor(sums[mt][1], d, 64);
            sums[mt][2] += __shfl_xor(sums[mt][2], d, 64);
            sums[mt][3] += __shfl_xor(sums[mt][3], d, 64);
        }
    if (l15 == 0) {
#pragma unroll
        for (int mt = 0; mt < 2; ++mt)
            *(f32x4*)&aggh[(size_t)(b * NP + p) * 32 + mt * 16 + 4 * g] = sums[mt];
    }
}

// ---------------- fo MLP + batch reduce, fused ----------------
// Grid: 64 blocks (one per batch) x 256 thr = 4 waves; wave w, pass q:
// nodes w*32 + q*16 + l15.
__global__ __launch_bounds__(256) void fo_reduce_kernel(
    const float* __restrict__ aggh, const _Float16* __restrict__ xt16,
    const _Float16* __restrict__ w3f,      // w3f(4096) || w4f(2048)
    const float* __restrict__ cs,
    float* __restrict__ out)
{
    __shared__ float red[128][33];
    __shared__ float red2[256];

    const int tid  = threadIdx.x;
    const int w    = tid >> 6;
    const int lane = tid & 63;
    const int g    = lane >> 4;
    const int l15  = lane & 15;
    const int b    = blockIdx.x;

#pragma unroll
    for (int q = 0; q < 2; ++q) {
        const int nl = w * 32 + q * 16 + l15;      // node-in-batch 0..127
        const size_t node = (size_t)b * NP + nl;

        // ---- B-frags of H^T: k 0..15 = x, 16..47 = agg, 48..63 = 0 ----
        f16x8 bfo[2];
        if (g < 2) {
            bfo[0] = *(const f16x8*)&xt16[node * 16 + g * 8];
            const float* a1 = &aggh[node * 32 + 16 + g * 8];
            f16x8 t1;
#pragma unroll
            for (int j = 0; j < 8; ++j) t1[j] = (_Float16)a1[j];
            bfo[1] = t1;
        } else {
            const float* a0 = &aggh[node * 32 + (g - 2) * 8];
            f16x8 t0;
#pragma unroll
            for (int j = 0; j < 8; ++j) t0[j] = (_Float16)a0[j];
            bfo[0] = t0;
            f16x8 zz = {};
            bfo[1] = zz;
        }

        // ---- fo0: C3^T = W3^T x H^T, acc init = c3 ----
        f32x4 acc3[4];
#pragma unroll
        for (int mt = 0; mt < 4; ++mt)
            acc3[mt] = *(const f32x4*)&cs[384 + mt * 16 + 4 * g];
#pragma unroll
        for (int ks = 0; ks < 2; ++ks)
#pragma unroll
            for (int mt = 0; mt < 4; ++mt) {
                f16x8 a3 = *(const f16x8*)&w3f[(((ks * 4 + g) * 64) + mt * 16 + l15) * 8];
                acc3[mt] = __builtin_amdgcn_mfma_f32_16x16x32_f16(a3, bfo[ks], acc3[mt], 0, 0, 0);
            }
        f16x2 pw3[4][2];
#pragma unroll
        for (int mt = 0; mt < 4; ++mt)
#pragma unroll
            for (int rp = 0; rp < 2; ++rp) {
                f16x2 hh = cvt_pk(acc3[mt][2 * rp], acc3[mt][2 * rp + 1]);
                f16x2 zz = {};
                pw3[mt][rp] = __builtin_elementwise_max(hh, zz);
            }
        // ---- fo1 via sigma handoff, acc init = c4 ----
        f32x4 acc4[2];
        acc4[0] = *(const f32x4*)&cs[512 + 0 * 16 + 4 * g];
        acc4[1] = *(const f32x4*)&cs[512 + 1 * 16 + 4 * g];
#pragma unroll
        for (int ks = 0; ks < 2; ++ks) {
            uint4 uu;
            uu.x = bc32(pw3[2 * ks][0]);
            uu.y = bc32(pw3[2 * ks][1]);
            uu.z = bc32(pw3[2 * ks + 1][0]);
            uu.w = bc32(pw3[2 * ks + 1][1]);
            f16x8 u = __builtin_bit_cast(f16x8, uu);
#pragma unroll
            for (int mt = 0; mt < 2; ++mt) {
                f16x8 a4 = *(const f16x8*)&w3f[4096 + (((ks * 4 + g) * 32) + mt * 16 + l15) * 8];
                acc4[mt] = __builtin_amdgcn_mfma_f32_16x16x32_f16(a4, u, acc4[mt], 0, 0, 0);
            }
        }
        // ---- epilogue: relu -> LDS ----
#pragma unroll
        for (int mt = 0; mt < 2; ++mt)
#pragma unroll
            for (int r = 0; r < 4; ++r)
                red[nl][mt * 16 + 4 * g + r] = fmaxf(acc4[mt][r], 0.f);
    }
    __syncthreads();

    // ---- reduce 128 nodes -> out[b][32] ----
    int m = tid & 31;
    int grp = tid >> 5;                // 8 groups
    float v = 0.f;
#pragma unroll
    for (int pn = 0; pn < 16; ++pn) v += red[grp * 16 + pn][m];
    red2[tid] = v;
    __syncthreads();
    if (grp < 4) red2[tid] += red2[tid + 128];
    __syncthreads();
    if (grp < 2) red2[tid] += red2[tid + 64];
    __syncthreads();
    if (grp == 0) out[b * 32 + m] = red2[tid] + red2[tid + 32];
}

extern "C" void kernel_launch(void* const* d_in, const int* in_sizes, int n_in,
                              void* d_out, int out_size, void* d_ws, size_t ws_size,
                              hipStream_t stream) {
    (void)in_sizes; (void)n_in; (void)out_size; (void)ws_size;
    const float* x    = (const float*)d_in[0];
    const float* fr0w = (const float*)d_in[1];
    const float* fr1w = (const float*)d_in[7];
    const float* fr2w = (const float*)d_in[13];
    const float* fo0w = (const float*)d_in[19];
    const float* fo1w = (const float*)d_in[25];

    float* ws = (float*)d_ws;
    float*    cs     = ws;                                   // 1024 f32
    _Float16* Rch    = (_Float16*)(ws + 1024);               // 786432 f16
    _Float16* Sc2    = (_Float16*)(ws + 394240);             // 786432 f16
    _Float16* w1f    = (_Float16*)(ws + 787456);             // 8192 f16 (w1f||w2f)
    _Float16* w3f    = (_Float16*)(ws + 791552);             // 6144 f16 (w3f||w4f)
    _Float16* xt16   = (_Float16*)(ws + 794688);             // 131072 f16
    float*    aggh   = ws + 860224;                          // 8192*32 f32
    float*    out    = (float*)d_out;

    prep_kernel<<<1625, 256, 0, stream>>>(x, fr0w, fr1w, fr2w, fo0w, fo1w,
        w1f, w3f, cs, xt16, Rch, Sc2,
        (const float*)d_in[2],  (const float*)d_in[3],  (const float*)d_in[4],
        (const float*)d_in[5],  (const float*)d_in[6],
        (const float*)d_in[8],  (const float*)d_in[9],  (const float*)d_in[10],
        (const float*)d_in[11], (const float*)d_in[12],
        (const float*)d_in[14], (const float*)d_in[15], (const float*)d_in[16],
        (const float*)d_in[17], (const float*)d_in[18],
        (const float*)d_in[20], (const float*)d_in[21], (const float*)d_in[22],
        (const float*)d_in[23], (const float*)d_in[24],
        (const float*)d_in[26], (const float*)d_in[27], (const float*)d_in[28],
        (const float*)d_in[29], (const float*)d_in[30]);

    edge_kernel<<<NB * 32, 256, 0, stream>>>(Rch, Sc2, w1f, cs, aggh);

    fo_reduce_kernel<<<NB, 256, 0, stream>>>(aggh, xt16, w3f, cs, out);
}

// Round 17
// 36.134 us; speedup vs baseline: 5.9237x; 1.1291x over previous
//
#include <hip/hip_runtime.h>

// GraphEmbeddings interaction network — swapped-operand MFMA, sigma in-register
// fr1->fr2 handoff. R17 = R16 with the bw2L staging guard fixed (tid < 256,
// not 128 — bw2L is 256 uint4s; half-staged weights caused R16's absmax blowup).

#define NB 64
#define NF 16
#define NP 128

typedef _Float16 f16x8 __attribute__((ext_vector_type(8)));
typedef _Float16 f16x4 __attribute__((ext_vector_type(4)));
typedef _Float16 f16x2 __attribute__((ext_vector_type(2)));
typedef float    f32x4 __attribute__((ext_vector_type(4)));

__device__ __forceinline__ f16x2 cvt_pk(float a, float b) {
    return __builtin_bit_cast(f16x2, __builtin_amdgcn_cvt_pkrtz(a, b));
}
__device__ __forceinline__ unsigned bc32(f16x2 h) {
    return __builtin_bit_cast(unsigned, h);
}

// ---------------- prep ----------------
// blocks 0..767   : Rc ([node][96]) and Sc2 (k-planes), fp16 — 4 ch per thread
// block 768       : consts c1 (cs+192,f32), c2 (cs+352), c3 (cs+384), c4 (cs+512)
// blocks 769..800 : w1f (W1^T s1-scaled frags) + w2f (sigma, s2-scaled)
// blocks 801..824 : w3f (fo0^T s3-scaled, K 48->64 zero-pad) + w4f (sigma, s4)
// blocks 825..856 : xt16[node][16] transpose of x
__global__ void prep_kernel(const float* __restrict__ x, const float* __restrict__ w0,
                            const float* __restrict__ w1, const float* __restrict__ w2,
                            const float* __restrict__ w3, const float* __restrict__ w4,
                            _Float16* __restrict__ w1f, _Float16* __restrict__ w3f,
                            float* __restrict__ cs, _Float16* __restrict__ xt16,
                            _Float16* __restrict__ Rch, _Float16* __restrict__ Sc2,
    const float* b0, const float* g0, const float* be0, const float* m0, const float* v0,
    const float* b1, const float* g1, const float* be1, const float* m1, const float* v1,
    const float* b2, const float* g2, const float* be2, const float* m2, const float* v2,
    const float* b3, const float* g3, const float* be3, const float* m3, const float* v3,
    const float* b4, const float* g4, const float* be4, const float* m4, const float* v4)
{
    const int bi = blockIdx.x;
    const int t = threadIdx.x;
    if (bi < 768) {
        int idx = bi * 256 + t;            // B*P*24 (4 ch per thread)
        int c4i = idx % 24;
        int node = idx / 24;
        int p = node & (NP - 1);
        int b = node >> 7;
        int ch0 = c4i * 4;
        float sv4[4], cv4[4];
#pragma unroll
        for (int j = 0; j < 4; ++j) {
            float s = g0[ch0 + j] * rsqrtf(v0[ch0 + j] + 1e-3f);
            sv4[j] = s;
            cv4[j] = (b0[ch0 + j] - m0[ch0 + j]) * s + be0[ch0 + j];
        }
        const float* xb = x + b * NF * NP + p;
        f32x4 r = (f32x4){0.f, 0.f, 0.f, 0.f};
        f32x4 s = (f32x4){0.f, 0.f, 0.f, 0.f};
#pragma unroll
        for (int f = 0; f < NF; ++f) {
            float xv = xb[f * NP];
            f32x4 wr = *(const f32x4*)&w0[f * 96 + ch0];
            f32x4 ws = *(const f32x4*)&w0[(NF + f) * 96 + ch0];
            r += xv * wr;
            s += xv * ws;
        }
        f16x4 rv, sv;
#pragma unroll
        for (int j = 0; j < 4; ++j) {
            rv[j] = (_Float16)(r[j] * sv4[j] + cv4[j]);
            sv[j] = (_Float16)(s[j] * sv4[j]);
        }
        *(f16x4*)&Rch[node * 96 + ch0] = rv;
        int ks = ch0 >> 5;                 // 4-ch group never crosses a plane
        *(f16x4*)&Sc2[((b * 3 + ks) * NP + p) * 32 + (ch0 - ks * 32)] = sv;
    } else if (bi == 768) {
        if (t < 64) {                      // c1 f32
            float s = g1[t] * rsqrtf(v1[t] + 1e-3f);
            cs[192 + t] = (b1[t] - m1[t]) * s + be1[t];
        }
        if (t < 32) {                      // c2 f32
            float s = g2[t] * rsqrtf(v2[t] + 1e-3f);
            cs[352 + t] = (b2[t] - m2[t]) * s + be2[t];
        }
        if (t < 64) {                      // c3 f32
            float s = g3[t] * rsqrtf(v3[t] + 1e-3f);
            cs[384 + t] = (b3[t] - m3[t]) * s + be3[t];
        }
        if (t < 32) {                      // c4 f32
            float s = g4[t] * rsqrtf(v4[t] + 1e-3f);
            cs[512 + t] = (b4[t] - m4[t]) * s + be4[t];
        }
    } else if (bi < 801) {
        int i = (bi - 769) * 256 + t;         // 0..8191
        if (i < 6144) {                       // w1f[kb][n][j] = W1[kb*8+j][n]*s1[n]
            int j = i & 7, n = (i >> 3) & 63, kb = i >> 9;
            float s1 = g1[n] * rsqrtf(v1[n] + 1e-3f);
            w1f[i] = (_Float16)(w1[(kb * 8 + j) * 64 + n] * s1);
        } else {                              // w2f: sigma-permuted K, s2-scaled
            int i2 = i - 6144;
            int j = i2 & 7, n = (i2 >> 3) & 31, kb = i2 >> 8;
            int ks = kb >> 2, g = kb & 3;
            int src = (2 * ks + (j >> 2)) * 16 + 4 * g + (j & 3);
            float s2 = g2[n] * rsqrtf(v2[n] + 1e-3f);
            w1f[6144 + i2] = (_Float16)(w2[src * 32 + n] * s2);
        }
    } else if (bi < 825) {
        int i = (bi - 801) * 256 + t;         // 0..6143
        if (i < 4096) {                       // w3f[kb][n][j] = fo0[kb*8+j][n]*s3[n], pad k>=48
            int j = i & 7, n = (i >> 3) & 63, kb = i >> 9;
            int k = kb * 8 + j;
            float s3 = g3[n] * rsqrtf(v3[n] + 1e-3f);
            w3f[i] = (k < 48) ? (_Float16)(w3[k * 64 + n] * s3) : (_Float16)0.f;
        } else {                              // w4f: sigma-permuted, s4-scaled
            int i2 = i - 4096;
            int j = i2 & 7, n = (i2 >> 3) & 31, kb = i2 >> 8;
            int ks = kb >> 2, g = kb & 3;
            int src = (2 * ks + (j >> 2)) * 16 + 4 * g + (j & 3);
            float s4 = g4[n] * rsqrtf(v4[n] + 1e-3f);
            w3f[4096 + i2] = (_Float16)(w4[src * 32 + n] * s4);
        }
    } else {
        int n = (bi - 825) * 256 + t;         // 0..8191 nodes
        int b = n >> 7, pn = n & 127;
        _Float16 tmp[16];
#pragma unroll
        for (int f = 0; f < NF; ++f) tmp[f] = (_Float16)x[(b * NF + f) * NP + pn];
        *(f16x8*)&xt16[n * 16]     = *(f16x8*)&tmp[0];
        *(f16x8*)&xt16[n * 16 + 8] = *(f16x8*)&tmp[8];
    }
}

// ---------------- edge MLP: one wave = one receiver, 128 edges ----------------
// Grid: 1024 blocks x 512 thr = 8192 waves. Block = (b, 8 receivers).
// Sc2 slab (24 KB) staged once per block in padded LDS (stride 40 f16).
__global__ __launch_bounds__(512) void edge_kernel(
    const _Float16* __restrict__ Rch, const _Float16* __restrict__ Sc2,
    const _Float16* __restrict__ w1f,      // w1f(6144) || w2f(2048)
    const float* __restrict__ cs,
    float* __restrict__ aggh)              // [node][32] f32
{
    __shared__ _Float16 Sl[3 * 128 * 40];  // 30720 B padded slab
    __shared__ _Float16 bw2L[2048];        // 4 KB fr2 weight frags = 256 uint4

    const int tid  = threadIdx.x;
    const int w    = tid >> 6;             // 0..7
    const int lane = tid & 63;
    const int g    = lane >> 4;
    const int l15  = lane & 15;
    const int blk  = blockIdx.x;
    const int b    = blk >> 4;
    const int p    = (blk & 15) * 8 + w;

    // stage fr2 weights (256 uint4) + Sc2 slab (1536 uint4)
    if (tid < 256) ((uint4*)bw2L)[tid] = ((const uint4*)(w1f + 6144))[tid];
    {
        const uint4* src = (const uint4*)(Sc2 + (size_t)b * 3 * NP * 32);
#pragma unroll
        for (int i = 0; i < 3; ++i) {
            int idx = tid + i * 512;       // 0..1535
            int row = idx >> 2, c8 = idx & 3;
            *(uint4*)&Sl[row * 40 + c8 * 8] = src[idx];
        }
    }
    __syncthreads();

    // ---- fr1 weights + per-lane consts in registers ----
    f16x8 bw1[3][4];
#pragma unroll
    for (int ks = 0; ks < 3; ++ks)
#pragma unroll
        for (int mt = 0; mt < 4; ++mt)
            bw1[ks][mt] = *(const f16x8*)&w1f[(((ks * 4 + g) * 64) + mt * 16 + l15) * 8];
    f16x8 rc[3];
#pragma unroll
    for (int ks = 0; ks < 3; ++ks)
        rc[ks] = *(const f16x8*)&Rch[(size_t)(b * NP + p) * 96 + ks * 32 + g * 8];
    f16x2 c1pk[4][2];
#pragma unroll
    for (int mt = 0; mt < 4; ++mt) {
        f32x4 cf = *(const f32x4*)&cs[192 + mt * 16 + 4 * g];
        c1pk[mt][0] = cvt_pk(cf[0], cf[1]);
        c1pk[mt][1] = cvt_pk(cf[2], cf[3]);
    }
    f32x4 c2v[2];
#pragma unroll
    for (int mt = 0; mt < 2; ++mt)
        c2v[mt] = *(const f32x4*)&cs[352 + mt * 16 + 4 * g];

    f32x4 sums[2];
    sums[0] = (f32x4){0.f, 0.f, 0.f, 0.f};
    sums[1] = (f32x4){0.f, 0.f, 0.f, 0.f};

#pragma unroll
    for (int it = 0; it < 8; ++it) {
        const int row = it * 16 + l15;     // edge (sender) index
        // ---- E1^T B-frag from padded LDS slab ----
        f16x8 bf[3];
#pragma unroll
        for (int ks = 0; ks < 3; ++ks) {
            f16x8 sv = *(const f16x8*)&Sl[(ks * NP + row) * 40 + g * 8];
            f16x8 tv = sv + rc[ks];
            f16x8 zz = {};
            bf[ks] = __builtin_elementwise_max(tv, zz);
        }
        // ---- fr1: 12 MFMAs into acc[4] ----
        f32x4 acc[4];
#pragma unroll
        for (int mt = 0; mt < 4; ++mt) acc[mt] = (f32x4){0.f, 0.f, 0.f, 0.f};
#pragma unroll
        for (int ks = 0; ks < 3; ++ks)
#pragma unroll
            for (int mt = 0; mt < 4; ++mt)
                acc[mt] = __builtin_amdgcn_mfma_f32_16x16x32_f16(bw1[ks][mt], bf[ks], acc[mt], 0, 0, 0);
        // ---- epilogue 1: pack, +c1 (f16), relu ----
        f16x2 pw[4][2];
#pragma unroll
        for (int mt = 0; mt < 4; ++mt)
#pragma unroll
            for (int rp = 0; rp < 2; ++rp) {
                f16x2 hh = cvt_pk(acc[mt][2 * rp], acc[mt][2 * rp + 1]);
                hh = hh + c1pk[mt][rp];
                f16x2 zz = {};
                pw[mt][rp] = __builtin_elementwise_max(hh, zz);
            }
        // ---- fr2 via sigma handoff (weights from LDS), acc2 init = c2 ----
        f32x4 acc2[2];
        acc2[0] = c2v[0];
        acc2[1] = c2v[1];
#pragma unroll
        for (int ks = 0; ks < 2; ++ks) {
            uint4 uu;
            uu.x = bc32(pw[2 * ks][0]);
            uu.y = bc32(pw[2 * ks][1]);
            uu.z = bc32(pw[2 * ks + 1][0]);
            uu.w = bc32(pw[2 * ks + 1][1]);
            f16x8 u = __builtin_bit_cast(f16x8, uu);
#pragma unroll
            for (int mt = 0; mt < 2; ++mt) {
                f16x8 a2 = *(const f16x8*)&bw2L[(((ks * 4 + g) * 32) + mt * 16 + l15) * 8];
                acc2[mt] = __builtin_amdgcn_mfma_f32_16x16x32_f16(a2, u, acc2[mt], 0, 0, 0);
            }
        }
        // ---- epilogue 2: relu, accumulate senders != p ----
#pragma unroll
        for (int mt = 0; mt < 2; ++mt)
#pragma unroll
            for (int r = 0; r < 4; ++r) {
                float v = fmaxf(acc2[mt][r], 0.f);
                sums[mt][r] += (row != p) ? v : 0.f;
            }
    }

    // ---- reduce over the 16 edge-lanes within each group; store partials ----
#pragma unroll
    for (int mt = 0; mt < 2; ++mt)
#pragma unroll
        for (int d = 1; d <= 8; d <<= 1) {
            sums[mt][0] += __shfl_xor(sums[mt][0], d, 64);
            sums[mt][1] += __shfl_xor(sums[mt][1], d, 64);
            sums[mt][2] += __shfl_xor(sums[mt][2], d, 64);
            sums[mt][3] += __shfl_xor(sums[mt][3], d, 64);
        }
    if (l15 == 0) {
#pragma unroll
        for (int mt = 0; mt < 2; ++mt)
            *(f32x4*)&aggh[(size_t)(b * NP + p) * 32 + mt * 16 + 4 * g] = sums[mt];
    }
}

// ---------------- fo MLP + batch reduce, fused ----------------
// Grid: 64 blocks (one per batch) x 256 thr = 4 waves; wave w, pass q:
// nodes w*32 + q*16 + l15.
__global__ __launch_bounds__(256) void fo_reduce_kernel(
    const float* __restrict__ aggh, const _Float16* __restrict__ xt16,
    const _Float16* __restrict__ w3f,      // w3f(4096) || w4f(2048)
    const float* __restrict__ cs,
    float* __restrict__ out)
{
    __shared__ float red[128][33];
    __shared__ float red2[256];

    const int tid  = threadIdx.x;
    const int w    = tid >> 6;
    const int lane = tid & 63;
    const int g    = lane >> 4;
    const int l15  = lane & 15;
    const int b    = blockIdx.x;

#pragma unroll
    for (int q = 0; q < 2; ++q) {
        const int nl = w * 32 + q * 16 + l15;      // node-in-batch 0..127
        const size_t node = (size_t)b * NP + nl;

        // ---- B-frags of H^T: k 0..15 = x, 16..47 = agg, 48..63 = 0 ----
        f16x8 bfo[2];
        if (g < 2) {
            bfo[0] = *(const f16x8*)&xt16[node * 16 + g * 8];
            const float* a1 = &aggh[node * 32 + 16 + g * 8];
            f16x8 t1;
#pragma unroll
            for (int j = 0; j < 8; ++j) t1[j] = (_Float16)a1[j];
            bfo[1] = t1;
        } else {
            const float* a0 = &aggh[node * 32 + (g - 2) * 8];
            f16x8 t0;
#pragma unroll
            for (int j = 0; j < 8; ++j) t0[j] = (_Float16)a0[j];
            bfo[0] = t0;
            f16x8 zz = {};
            bfo[1] = zz;
        }

        // ---- fo0: C3^T = W3^T x H^T, acc init = c3 ----
        f32x4 acc3[4];
#pragma unroll
        for (int mt = 0; mt < 4; ++mt)
            acc3[mt] = *(const f32x4*)&cs[384 + mt * 16 + 4 * g];
#pragma unroll
        for (int ks = 0; ks < 2; ++ks)
#pragma unroll
            for (int mt = 0; mt < 4; ++mt) {
                f16x8 a3 = *(const f16x8*)&w3f[(((ks * 4 + g) * 64) + mt * 16 + l15) * 8];
                acc3[mt] = __builtin_amdgcn_mfma_f32_16x16x32_f16(a3, bfo[ks], acc3[mt], 0, 0, 0);
            }
        f16x2 pw3[4][2];
#pragma unroll
        for (int mt = 0; mt < 4; ++mt)
#pragma unroll
            for (int rp = 0; rp < 2; ++rp) {
                f16x2 hh = cvt_pk(acc3[mt][2 * rp], acc3[mt][2 * rp + 1]);
                f16x2 zz = {};
                pw3[mt][rp] = __builtin_elementwise_max(hh, zz);
            }
        // ---- fo1 via sigma handoff, acc init = c4 ----
        f32x4 acc4[2];
        acc4[0] = *(const f32x4*)&cs[512 + 0 * 16 + 4 * g];
        acc4[1] = *(const f32x4*)&cs[512 + 1 * 16 + 4 * g];
#pragma unroll
        for (int ks = 0; ks < 2; ++ks) {
            uint4 uu;
            uu.x = bc32(pw3[2 * ks][0]);
            uu.y = bc32(pw3[2 * ks][1]);
            uu.z = bc32(pw3[2 * ks + 1][0]);
            uu.w = bc32(pw3[2 * ks + 1][1]);
            f16x8 u = __builtin_bit_cast(f16x8, uu);
#pragma unroll
            for (int mt = 0; mt < 2; ++mt) {
                f16x8 a4 = *(const f16x8*)&w3f[4096 + (((ks * 4 + g) * 32) + mt * 16 + l15) * 8];
                acc4[mt] = __builtin_amdgcn_mfma_f32_16x16x32_f16(a4, u, acc4[mt], 0, 0, 0);
            }
        }
        // ---- epilogue: relu -> LDS ----
#pragma unroll
        for (int mt = 0; mt < 2; ++mt)
#pragma unroll
            for (int r = 0; r < 4; ++r)
                red[nl][mt * 16 + 4 * g + r] = fmaxf(acc4[mt][r], 0.f);
    }
    __syncthreads();

    // ---- reduce 128 nodes -> out[b][32] ----
    int m = tid & 31;
    int grp = tid >> 5;                // 8 groups
    float v = 0.f;
#pragma unroll
    for (int pn = 0; pn < 16; ++pn) v += red[grp * 16 + pn][m];
    red2[tid] = v;
    __syncthreads();
    if (grp < 4) red2[tid] += red2[tid + 128];
    __syncthreads();
    if (grp < 2) red2[tid] += red2[tid + 64];
    __syncthreads();
    if (grp == 0) out[b * 32 + m] = red2[tid] + red2[tid + 32];
}

extern "C" void kernel_launch(void* const* d_in, const int* in_sizes, int n_in,
                              void* d_out, int out_size, void* d_ws, size_t ws_size,
                              hipStream_t stream) {
    (void)in_sizes; (void)n_in; (void)out_size; (void)ws_size;
    const float* x    = (const float*)d_in[0];
    const float* fr0w = (const float*)d_in[1];
    const float* fr1w = (const float*)d_in[7];
    const float* fr2w = (const float*)d_in[13];
    const float* fo0w = (const float*)d_in[19];
    const float* fo1w = (const float*)d_in[25];

    float* ws = (float*)d_ws;
    float*    cs     = ws;                                   // 1024 f32
    _Float16* Rch    = (_Float16*)(ws + 1024);               // 786432 f16
    _Float16* Sc2    = (_Float16*)(ws + 394240);             // 786432 f16
    _Float16* w1f    = (_Float16*)(ws + 787456);             // 8192 f16 (w1f||w2f)
    _Float16* w3f    = (_Float16*)(ws + 791552);             // 6144 f16 (w3f||w4f)
    _Float16* xt16   = (_Float16*)(ws + 794688);             // 131072 f16
    float*    aggh   = ws + 860224;                          // 8192*32 f32
    float*    out    = (float*)d_out;

    prep_kernel<<<857, 256, 0, stream>>>(x, fr0w, fr1w, fr2w, fo0w, fo1w,
        w1f, w3f, cs, xt16, Rch, Sc2,
        (const float*)d_in[2],  (const float*)d_in[3],  (const float*)d_in[4],
        (const float*)d_in[5],  (const float*)d_in[6],
        (const float*)d_in[8],  (const float*)d_in[9],  (const float*)d_in[10],
        (const float*)d_in[11], (const float*)d_in[12],
        (const float*)d_in[14], (const float*)d_in[15], (const float*)d_in[16],
        (const float*)d_in[17], (const float*)d_in[18],
        (const float*)d_in[20], (const float*)d_in[21], (const float*)d_in[22],
        (const float*)d_in[23], (const float*)d_in[24],
        (const float*)d_in[26], (const float*)d_in[27], (const float*)d_in[28],
        (const float*)d_in[29], (const float*)d_in[30]);

    edge_kernel<<<NB * 16, 512, 0, stream>>>(Rch, Sc2, w1f, cs, aggh);

    fo_reduce_kernel<<<NB, 256, 0, stream>>>(aggh, xt16, w3f, cs, out);
}